// Round 4
// baseline (24.157 us; speedup 1.0000x reference)
//
#include <hip/hip_runtime.h>

// EvenLayer (neural BP even/check layer), MI355X — R4.
//
// Block-diagonal structure (mask = kron(eye(256), ones(16,16)-eye(16))):
// per (batch b, check c): la[j]=logf(|x_j|+eps); parity of sign bits;
// acc[i] = sum_j la[j]*W_c[j][i] (diag zeroed); out = logf((1+m+eps)/(1-m+eps)).
//
// R4: R2's 1-thread-per-task math (bit-exact lineage, absmax 0.0) + software
// pipelining to break the phase-aligned burst structure:
//   issue x0 loads -> issue W loads -> compute la0 (hides W latency)
//   -> W diag-zero + LDS write -> issue x1 loads -> barrier
//   -> matvec0/epi0/store0 (x1 streams behind) -> la1/matvec1/epi1/store1
//     (store0 drains behind compute1)
// Per-output fmaf chain and transcendental sequence identical to R2.

constexpr int M_CHECKS = 256;
constexpr int DC = 16;
constexpr int NEURONS = M_CHECKS * DC;   // 4096
constexpr int BATCH = 1024;
constexpr float EPS = 1e-8f;

constexpr int CB = 16;    // checks per block
constexpr int BB = 16;    // batches per set
constexpr int SETS = 2;   // pipelined batch-sets per block
constexpr int BS4 = 65;   // float4 stride per check in Wsh (proven conflict-free)

__device__ __forceinline__ void matvec_epi_store(
    const float4* __restrict__ wrow,  // &Wsh[ci*BS4]
    const float la[DC], const int sbits, float* __restrict__ op)
{
    float acc[DC];
    #pragma unroll
    for (int i = 0; i < DC; ++i) acc[i] = 0.0f;

    #pragma unroll
    for (int j = 0; j < DC; ++j) {
        const float lj = la[j];
        const float4 w0 = wrow[j * 4 + 0];
        const float4 w1 = wrow[j * 4 + 1];
        const float4 w2 = wrow[j * 4 + 2];
        const float4 w3 = wrow[j * 4 + 3];
        acc[0]  = fmaf(lj, w0.x, acc[0]);
        acc[1]  = fmaf(lj, w0.y, acc[1]);
        acc[2]  = fmaf(lj, w0.z, acc[2]);
        acc[3]  = fmaf(lj, w0.w, acc[3]);
        acc[4]  = fmaf(lj, w1.x, acc[4]);
        acc[5]  = fmaf(lj, w1.y, acc[5]);
        acc[6]  = fmaf(lj, w1.z, acc[6]);
        acc[7]  = fmaf(lj, w1.w, acc[7]);
        acc[8]  = fmaf(lj, w2.x, acc[8]);
        acc[9]  = fmaf(lj, w2.y, acc[9]);
        acc[10] = fmaf(lj, w2.z, acc[10]);
        acc[11] = fmaf(lj, w2.w, acc[11]);
        acc[12] = fmaf(lj, w3.x, acc[12]);
        acc[13] = fmaf(lj, w3.y, acc[13]);
        acc[14] = fmaf(lj, w3.z, acc[14]);
        acc[15] = fmaf(lj, w3.w, acc[15]);
    }

    const int sall = __popc(sbits) & 1;

    #define EPI(RCOMP, I)                                                   \
        { const float e_ = expf(acc[I]);                                    \
          const int par_ = sall ^ ((sbits >> (I)) & 1);                     \
          const float even_ = par_ ? -e_ : e_;                              \
          RCOMP = logf((1.0f + even_ + EPS) / (1.0f - even_ + EPS)); }

    #pragma unroll
    for (int k = 0; k < 4; ++k) {
        float4 r;
        EPI(r.x, 4 * k + 0)
        EPI(r.y, 4 * k + 1)
        EPI(r.z, 4 * k + 2)
        EPI(r.w, 4 * k + 3)
        *(float4*)(op + 4 * k) = r;
    }
    #undef EPI
}

__device__ __forceinline__ void log_abs_pack(
    const float4 xv[4], float la[DC], int& sbits)
{
    const float xs[16] = {xv[0].x, xv[0].y, xv[0].z, xv[0].w,
                          xv[1].x, xv[1].y, xv[1].z, xv[1].w,
                          xv[2].x, xv[2].y, xv[2].z, xv[2].w,
                          xv[3].x, xv[3].y, xv[3].z, xv[3].w};
    sbits = 0;
    #pragma unroll
    for (int j = 0; j < DC; ++j) {
        la[j] = logf(fabsf(xs[j]) + EPS);
        if (xs[j] < 0.0f) sbits |= (1 << j);
    }
}

__global__ __launch_bounds__(256) void even_layer_kernel(
    const float* __restrict__ x,      // [BATCH, NEURONS]
    const float* __restrict__ w,      // [NEURONS, NEURONS], only block-diag used
    float* __restrict__ out)          // [BATCH, NEURONS]
{
    __shared__ float4 Wsh[CB * BS4];  // 16.6 KB

    const int tid = (int)threadIdx.x;
    const int cb  = (int)blockIdx.x & 15;   // check-group 0..15
    const int bg  = (int)blockIdx.x >> 4;   // batch-group 0..31 (32 batches each)

    const int bi = tid >> 4;                // local batch 0..15
    const int ci = tid & 15;                // local check 0..15 (fast => coalesced)
    const int b0 = bg * (SETS * BB) + bi;   // set-0 batch
    const int b1 = b0 + BB;                 // set-1 batch
    const int c  = cb * CB + ci;

    const float* xp0 = x + (size_t)b0 * NEURONS + (size_t)(c * DC);
    const float* xp1 = x + (size_t)b1 * NEURONS + (size_t)(c * DC);

    // ---- (1) issue set-0 x loads ----
    float4 xv0[4];
    #pragma unroll
    for (int k = 0; k < 4; ++k) xv0[k] = *(const float4*)(xp0 + 4 * k);

    // ---- (2) issue W row loads (into regs; latency hidden under la0) ----
    const int cl = tid >> 4;                // local check whose row this thread stages
    const int jr = tid & 15;                // row within that check's 16x16 block
    const int cc = cb * CB + cl;
    const float* wsrc = w + (size_t)(cc * DC + jr) * NEURONS + (size_t)(cc * DC);
    float4 wreg[4];
    #pragma unroll
    for (int k = 0; k < 4; ++k) wreg[k] = *(const float4*)(wsrc + 4 * k);

    // ---- (3) la0 + sign bits (needs only x0; W still in flight) ----
    float la0[DC]; int sb0;
    log_abs_pack(xv0, la0, sb0);

    // ---- (4) diag-zero (== mask) and write W to LDS ----
    #pragma unroll
    for (int k = 0; k < 4; ++k) {
        float4 wv = wreg[k];
        if ((jr >> 2) == k) {
            if ((jr & 3) == 0) wv.x = 0.0f;
            else if ((jr & 3) == 1) wv.y = 0.0f;
            else if ((jr & 3) == 2) wv.z = 0.0f;
            else wv.w = 0.0f;
        }
        Wsh[cl * BS4 + jr * 4 + k] = wv;
    }

    // ---- (5) issue set-1 x loads (stream behind set-0 compute) ----
    float4 xv1[4];
    #pragma unroll
    for (int k = 0; k < 4; ++k) xv1[k] = *(const float4*)(xp1 + 4 * k);

    __syncthreads();

    // ---- (6) set-0 matvec + epilogue + store ----
    const float4* wrow = &Wsh[ci * BS4];
    matvec_epi_store(wrow, la0, sb0,
                     out + (size_t)b0 * NEURONS + (size_t)(c * DC));

    // ---- (7) set-1: la, matvec, epilogue, store (store0 drains behind) ----
    float la1[DC]; int sb1;
    log_abs_pack(xv1, la1, sb1);
    matvec_epi_store(wrow, la1, sb1,
                     out + (size_t)b1 * NEURONS + (size_t)(c * DC));
}

extern "C" void kernel_launch(void* const* d_in, const int* in_sizes, int n_in,
                              void* d_out, int out_size, void* d_ws, size_t ws_size,
                              hipStream_t stream) {
    const float* x = (const float*)d_in[0];          // [1024, 4096]
    const float* w = (const float*)d_in[1];          // [4096, 4096] even_weights
    // d_in[2] = w_even2odd_mask: structure hard-coded, never read
    float* out = (float*)d_out;                      // [1024, 4096] f32

    dim3 grid((BATCH / (SETS * BB)) * (M_CHECKS / CB));  // 32 * 16 = 512 blocks
    dim3 block(256);
    hipLaunchKernelGGL(even_layer_kernel, grid, block, 0, stream, x, w, out);
}